// Round 4
// baseline (385.039 us; speedup 1.0000x reference)
//
#include <hip/hip_runtime.h>
#include <math.h>

#define B_ 64
#define T_ 1024
#define D_ 768
#define A_ 128

typedef __attribute__((ext_vector_type(4))) float f32x4;
typedef __attribute__((ext_vector_type(8))) short s16x8;
typedef __attribute__((ext_vector_type(4))) short s16x4;

__device__ inline short f2b(float f) {
  union { float f; unsigned u; } v; v.f = f;
  unsigned r = (v.u + 0x7FFFu + ((v.u >> 16) & 1u)) >> 16;
  return (short)r;
}
__device__ inline float b2f(short s) {
  union { unsigned u; float f; } v; v.u = ((unsigned)(unsigned short)s) << 16;
  return v.f;
}

__device__ inline void gll16(const void* g, const void* lds) {
  __builtin_amdgcn_global_load_lds(
      (const __attribute__((address_space(1))) unsigned*)g,
      (__attribute__((address_space(3))) unsigned*)lds, 16, 0, 0);
}

// ---------------------------------------------------------------------------
// bf16 MFMA GEMM: C[M,N] = A[M,K] @ Bt[N,K]^T
// 128x128 tile, BK=64, 256 threads (4 waves), 2-phase double-buffered LDS:
//   prologue stage buf0; loop { stage buf^1 (t+1); compute buf (t); barrier }
// One barrier per K-step; vmcnt drain at barrier lands AFTER the MFMA cluster.
// XCD batch-affinity swizzle (bijective, m204).
// ---------------------------------------------------------------------------
template<bool BF32, bool TANH_, bool WT, bool OB16>
__global__ __launch_bounds__(256, 2)
void gemm_bt(const short* __restrict__ Ab, const void* __restrict__ Bv,
             void* __restrict__ Cv, int M, int N, int K,
             long sA, long sB, long sC, int gx, int gy) {
  __shared__ __align__(16) short As0[128 * 64];
  __shared__ __align__(16) short Bs0[128 * 64];
  __shared__ __align__(16) short As1[128 * 64];
  __shared__ __align__(16) short Bs1[128 * 64];
  // ---- bijective XCD swizzle ----
  unsigned nwg = gridDim.x;
  unsigned L = blockIdx.x;
  unsigned xcd = L & 7u, base = L >> 3;
  unsigned q = nwg >> 3, r = nwg & 7u;
  unsigned id = (xcd < r ? xcd * (q + 1) : r * (q + 1) + (xcd - r) * q) + base;
  const int gxy = gx * gy;
  const int bz = id / gxy;
  const int rem = id - bz * gxy;
  const int by = rem / gx;
  const int bx = rem - by * gx;

  const int tid = threadIdx.x;
  const int w = tid >> 6, lane = tid & 63;
  const int n0 = bx * 128, m0 = by * 128;
  const int wr = w >> 1, wc = w & 1;
  const int lr = lane & 15, lq = lane >> 4;
  const short* A = Ab + (size_t)sA * bz;
  const short* Bb16 = nullptr; const float* Bf32 = nullptr;
  if (BF32) Bf32 = (const float*)Bv + (size_t)sB * bz;
  else      Bb16 = (const short*)Bv + (size_t)sB * bz;

  f32x4 acc[4][4] = {};

  const int r8 = lane >> 3, c8 = lane & 7;

// stage A+B tile for k-offset K0 into AS/BS
#define STAGE_TILE(AS, BS, K0)                                                 \
  {                                                                            \
    _Pragma("unroll")                                                          \
    for (int i = 0; i < 4; ++i) {                                              \
      int chunk = w * 4 + i;                                                   \
      int row = chunk * 8 + r8;                                                \
      gll16(A + (size_t)(m0 + row) * K + (K0) + c8 * 8, (AS) + chunk * 512);   \
    }                                                                          \
    if (!BF32) {                                                               \
      _Pragma("unroll")                                                        \
      for (int i = 0; i < 4; ++i) {                                            \
        int chunk = w * 4 + i;                                                 \
        int row = chunk * 8 + r8;                                              \
        gll16(Bb16 + (size_t)(n0 + row) * K + (K0) + c8 * 8, (BS) + chunk * 512); \
      }                                                                        \
    } else {                                                                   \
      _Pragma("unroll")                                                        \
      for (int u = 0; u < 4; ++u) {                                            \
        int c = tid * 4 + u;                                                   \
        int row = c >> 3, k8 = c & 7;                                          \
        const float* gp = Bf32 + (size_t)(n0 + row) * K + (K0) + k8 * 8;       \
        float4 f0 = *(const float4*)gp;                                        \
        float4 f1 = *(const float4*)(gp + 4);                                  \
        s16x8 p;                                                               \
        p[0] = f2b(f0.x); p[1] = f2b(f0.y); p[2] = f2b(f0.z); p[3] = f2b(f0.w);\
        p[4] = f2b(f1.x); p[5] = f2b(f1.y); p[6] = f2b(f1.z); p[7] = f2b(f1.w);\
        *(s16x8*)&(BS)[row * 64 + k8 * 8] = p;                                 \
      }                                                                        \
    }                                                                          \
  }

// compute one BK=64 tile from AS/BS into acc
#define COMPUTE_TILE(AS, BS)                                                   \
  {                                                                            \
    _Pragma("unroll")                                                          \
    for (int kk = 0; kk < 2; ++kk) {                                           \
      s16x8 a[4], b[4];                                                        \
      _Pragma("unroll")                                                        \
      for (int mf = 0; mf < 4; ++mf)                                           \
        a[mf] = *(const s16x8*)&(AS)[(wr * 64 + mf * 16 + lr) * 64 + kk * 32 + lq * 8]; \
      _Pragma("unroll")                                                        \
      for (int nf = 0; nf < 4; ++nf)                                           \
        b[nf] = *(const s16x8*)&(BS)[(wc * 64 + nf * 16 + lr) * 64 + kk * 32 + lq * 8]; \
      _Pragma("unroll")                                                        \
      for (int mf = 0; mf < 4; ++mf)                                           \
        _Pragma("unroll")                                                      \
        for (int nf = 0; nf < 4; ++nf)                                         \
          acc[mf][nf] = __builtin_amdgcn_mfma_f32_16x16x32_bf16(               \
              a[mf], b[nf], acc[mf][nf], 0, 0, 0);                             \
    }                                                                          \
  }

  // prologue
  STAGE_TILE(As0, Bs0, 0);
  __syncthreads();
  // paired 2-phase main loop (K/64 is even for all call sites)
  for (int k0 = 0; k0 < K; k0 += 128) {
    if (k0 + 64 < K) STAGE_TILE(As1, Bs1, k0 + 64);
    COMPUTE_TILE(As0, Bs0);
    __syncthreads();
    if (k0 + 128 < K) STAGE_TILE(As0, Bs0, k0 + 128);
    COMPUTE_TILE(As1, Bs1);
    __syncthreads();
  }

#undef STAGE_TILE
#undef COMPUTE_TILE

  // ---- epilogue; C/D layout: col = lane&15, row = (lane>>4)*4 + q ----
  if (WT) {
    if (OB16) {
      short* C = (short*)Cv + (size_t)sC * bz;
#pragma unroll
      for (int mf = 0; mf < 4; ++mf)
#pragma unroll
        for (int nf = 0; nf < 4; ++nf) {
          int mbase = m0 + wr * 64 + mf * 16 + lq * 4;
          int n = n0 + wc * 64 + nf * 16 + lr;
          s16x4 pk;
#pragma unroll
          for (int qq = 0; qq < 4; ++qq) {
            float v = acc[mf][nf][qq];
            if (TANH_) v = tanhf(v);
            pk[qq] = f2b(v);
          }
          *(s16x4*)(C + (size_t)n * M + mbase) = pk;
        }
    } else {
      float* C = (float*)Cv + (size_t)sC * bz;
#pragma unroll
      for (int mf = 0; mf < 4; ++mf)
#pragma unroll
        for (int nf = 0; nf < 4; ++nf) {
          int mbase = m0 + wr * 64 + mf * 16 + lq * 4;
          int n = n0 + wc * 64 + nf * 16 + lr;
#pragma unroll
          for (int qq = 0; qq < 4; ++qq) {
            float v = acc[mf][nf][qq];
            if (TANH_) v = tanhf(v);
            C[(size_t)n * M + mbase + qq] = v;
          }
        }
    }
  } else {
    float* C = (float*)Cv + (size_t)sC * bz;
#pragma unroll
    for (int mf = 0; mf < 4; ++mf)
#pragma unroll
      for (int nf = 0; nf < 4; ++nf) {
        int m = m0 + wr * 64 + mf * 16 + lq * 4;
        int n = n0 + wc * 64 + nf * 16 + lr;
#pragma unroll
        for (int qq = 0; qq < 4; ++qq) {
          float v = acc[mf][nf][qq];
          if (TANH_) v = tanhf(v);
          C[(size_t)(m + qq) * N + n] = v;
        }
      }
  }
}

// ---------------------------------------------------------------------------
// transpose + fp32->bf16: src [z][R][C] fp32 -> dst [z][C][R] bf16. 64x64 tiles.
// ---------------------------------------------------------------------------
__global__ __launch_bounds__(256)
void transpose_cvt(const float* __restrict__ src, short* __restrict__ dst,
                   int R, int C) {
  __shared__ float sh[64][68];
  const int tid = threadIdx.x;
  const float* s = src + (size_t)blockIdx.z * R * C;
  short* d = dst + (size_t)blockIdx.z * R * C;
  const int r0 = blockIdx.y * 64, c0 = blockIdx.x * 64;
#pragma unroll
  for (int u = 0; u < 4; ++u) {
    int e = tid + u * 256;
    int rr = e >> 4, cc4 = (e & 15) * 4;
    *(float4*)&sh[rr][cc4] = *(const float4*)&s[(size_t)(r0 + rr) * C + c0 + cc4];
  }
  __syncthreads();
#pragma unroll
  for (int u = 0; u < 4; ++u) {
    int e = tid + u * 256;
    int dr = e >> 4, tc4 = (e & 15) * 4;
    s16x4 pk;
#pragma unroll
    for (int j = 0; j < 4; ++j) pk[j] = f2b(sh[tc4 + j][dr]);
    *(s16x4*)&d[(size_t)(c0 + dr) * R + r0 + tc4] = pk;
  }
}

// ---------------------------------------------------------------------------
// in-place row softmax on bf16 [nb][T][T]; one wave per row, 16 elems/lane
// ---------------------------------------------------------------------------
__global__ __launch_bounds__(256)
void softmax_rows(short* __restrict__ St) {
  const int w = threadIdx.x >> 6, lane = threadIdx.x & 63;
  short* rp = St + ((size_t)blockIdx.y * T_ + blockIdx.x * 4 + w) * T_;
  s16x8 v0 = *(const s16x8*)&rp[lane * 16];
  s16x8 v1 = *(const s16x8*)&rp[lane * 16 + 8];
  float f[16];
#pragma unroll
  for (int j = 0; j < 8; ++j) { f[j] = b2f(v0[j]); f[j + 8] = b2f(v1[j]); }
  float m = f[0];
#pragma unroll
  for (int j = 1; j < 16; ++j) m = fmaxf(m, f[j]);
#pragma unroll
  for (int o = 32; o; o >>= 1) m = fmaxf(m, __shfl_xor(m, o));
  float ssum = 0.f;
#pragma unroll
  for (int j = 0; j < 16; ++j) { f[j] = __expf(f[j] - m); ssum += f[j]; }
#pragma unroll
  for (int o = 32; o; o >>= 1) ssum += __shfl_xor(ssum, o);
  float inv = 1.0f / ssum;
#pragma unroll
  for (int j = 0; j < 8; ++j) { v0[j] = f2b(f[j] * inv); v1[j] = f2b(f[j + 8] * inv); }
  *(s16x8*)&rp[lane * 16] = v0;
  *(s16x8*)&rp[lane * 16 + 8] = v1;
}

extern "C" void kernel_launch(void* const* d_in, const int* in_sizes, int n_in,
                              void* d_out, int out_size, void* d_ws, size_t ws_size,
                              hipStream_t stream) {
  const float* x  = (const float*)d_in[0];   // [B,T,D]
  const float* W1 = (const float*)d_in[1];   // [D,A]
  const float* W2 = (const float*)d_in[2];   // [A,T]
  float* out = (float*)d_out;                // [B,T,D] fp32

  // ws layout (bf16/shorts): xt[B,D,T] | W1t[A,D] | W2t[T,A] | H[B,T,A] | St[nb,T,T]
  short* xt  = (short*)d_ws;
  short* W1t = xt + (size_t)B_ * D_ * T_;
  short* W2t = W1t + (size_t)A_ * D_;
  short* H   = W2t + (size_t)T_ * A_;
  short* St  = H + (size_t)B_ * T_ * A_;
  size_t fixed_bytes = (size_t)(St - xt) * sizeof(short);
  long avail = (long)ws_size - (long)fixed_bytes;
  long per_b = (long)T_ * T_ * sizeof(short);
  int chunk = (int)(avail > 0 ? avail / per_b : 0);
  if (chunk > B_) chunk = B_;
  if (chunk < 1) chunk = 1;

  // prep: transposed bf16 copies
  transpose_cvt<<<dim3(D_ / 64, T_ / 64, B_), 256, 0, stream>>>(x, xt, T_, D_);
  transpose_cvt<<<dim3(A_ / 64, D_ / 64, 1), 256, 0, stream>>>(W1, W1t, D_, A_);
  transpose_cvt<<<dim3(T_ / 64, A_ / 64, 1), 256, 0, stream>>>(W2, W2t, A_, T_);

  // G1: H^T = W1t @ x^T (M=A,N=T,K=D), transposed write -> H[t][a] bf16, tanh
  gemm_bt<true, true, true, true><<<(T_ / 128) * (A_ / 128) * B_, 256, 0, stream>>>(
      W1t, x, H, A_, T_, D_, 0, (long)T_ * D_, (long)T_ * A_,
      T_ / 128, A_ / 128);

  for (int b0 = 0; b0 < B_; b0 += chunk) {
    int nb = B_ - b0; if (nb > chunk) nb = chunk;
    // G2: S[t,s] = H @ W2t^T (M=T,N=T,K=A), transposed write -> St[s][t] bf16
    gemm_bt<false, false, true, true><<<(T_ / 128) * (T_ / 128) * nb, 256, 0, stream>>>(
        H + (size_t)b0 * T_ * A_, W2t, St, T_, T_, A_,
        (long)T_ * A_, 0, (long)T_ * T_,
        T_ / 128, T_ / 128);
    // softmax over t = rows of St, in place, bf16 out
    softmax_rows<<<dim3(T_ / 4, nb), 256, 0, stream>>>(St);
    // G4: out[s,d] = Pt @ xt^T (M=T,N=D,K=T), fp32 write
    gemm_bt<false, false, false, false><<<(D_ / 128) * (T_ / 128) * nb, 256, 0, stream>>>(
        St, xt + (size_t)b0 * (size_t)D_ * T_, out + (size_t)b0 * (size_t)T_ * D_,
        T_, D_, T_, (long)T_ * T_, (long)D_ * T_, (long)T_ * D_,
        D_ / 128, T_ / 128);
  }
}

// Round 5
// 355.690 us; speedup vs baseline: 1.0825x; 1.0825x over previous
//
#include <hip/hip_runtime.h>
#include <math.h>

#define B_ 64
#define T_ 1024
#define D_ 768
#define A_ 128

typedef __attribute__((ext_vector_type(4))) float f32x4;
typedef __attribute__((ext_vector_type(8))) short s16x8;
typedef __attribute__((ext_vector_type(4))) short s16x4;

__device__ inline short f2b(float f) {
  union { float f; unsigned u; } v; v.f = f;
  unsigned r = (v.u + 0x7FFFu + ((v.u >> 16) & 1u)) >> 16;
  return (short)r;
}
__device__ inline float b2f(short s) {
  union { unsigned u; float f; } v; v.u = ((unsigned)(unsigned short)s) << 16;
  return v.f;
}

__device__ inline void gll16(const void* g, const void* lds) {
  __builtin_amdgcn_global_load_lds(
      (const __attribute__((address_space(1))) unsigned*)g,
      (__attribute__((address_space(3))) unsigned*)lds, 16, 0, 0);
}

// ---------------------------------------------------------------------------
// G4: 256x256-tile, BK=64, 8-wave (512thr), 8-phase counted-vmcnt bf16 GEMM.
// C[1024,768] = A[1024,1024](St bf16) @ B^T, Bt[768,1024](xt bf16). Per-batch.
// T2 st-swizzle: LDS[r][slot] holds global k-group (slot ^ (r&7)); source
// address pre-swizzled (gload_lds dest stays linear, rule #21); ds_read
// applies same XOR -> 2-way banked (free).
// Schedule per iter (tiles 2j->buf0 ph1-4, 2j+1->buf1 ph5-8); staging:
//   ph1: t(2j+1).A1 | ph2: t(2j+2).B0 | ph3: t(2j+2).B1 | ph4: t(2j+2).A0 +vmcnt(6)
//   ph5: t(2j+2).A1 | ph6: t(2j+3).B0 | ph7: t(2j+3).B1 | ph8: t(2j+3).A0 +vmcnt(6)
// B-halves of buf p are only read at the K-tile's first phase -> staging them
// right after is safe; A-halves staged last (their readers span all 4 phases).
// vmcnt(6)=3 half-tiles in flight guarantees next tile landed (per-wave count
// + barrier makes it cross-wave). Final iter peeled: stage only t15.A1, vmcnt(0).
// ---------------------------------------------------------------------------
__global__ __launch_bounds__(512, 2)
void gemm4_8ph(const short* __restrict__ Ag, const short* __restrict__ Bg,
               float* __restrict__ Cg) {
  __shared__ __align__(16) short AS[2][16384];
  __shared__ __align__(16) short BS[2][16384];
  // bijective XCD swizzle
  unsigned nwg = gridDim.x;
  unsigned L = blockIdx.x;
  unsigned xcd = L & 7u, base = L >> 3;
  unsigned q = nwg >> 3, r = nwg & 7u;
  unsigned id = (xcd < r ? xcd * (q + 1) : r * (q + 1) + (xcd - r) * q) + base;
  const int bz = id / 12;
  const int rem = id - bz * 12;
  const int by = rem / 3, bx = rem - (rem / 3) * 3;
  const int m0 = by * 256, n0 = bx * 256;

  const short* Ab = Ag + (size_t)bz * (T_ * T_);
  const short* Bb = Bg + (size_t)bz * (D_ * T_);
  float* Cb = Cg + (size_t)bz * (T_ * D_);

  const int tid = threadIdx.x;
  const int w = tid >> 6, lane = tid & 63;
  const int wr = w >> 2, wc = w & 3;
  const int lr = lane & 15, lq = lane >> 4;
  const int swzk = (lane & 7) ^ ((lane >> 3) & 7);   // source pre-swizzle
  const int abase = (wr * 128 + lr) * 64;
  const int bbase = (wc * 64 + lr) * 64;
  const int sx = lr & 7;
  const int sl0 = (lq ^ sx) * 8;          // kk=0 swizzled slot (shorts)
  const int sl1 = ((4 + lq) ^ sx) * 8;    // kk=1

  f32x4 acc[8][4] = {};
  s16x8 bq[4][2];

#define STG(dst, src, r0, kt)                                                  \
  { _Pragma("unroll")                                                          \
    for (int jj = 0; jj < 2; ++jj) {                                           \
      int rr = jj * 64 + w * 8 + (lane >> 3);                                  \
      gll16((src) + (size_t)((r0) + rr) * 1024 + (kt) + swzk * 8,              \
            (dst) + jj * 4096 + w * 512);                                      \
    } }

#define PHASE(P, Q, VM, STAGE)                                                 \
  {                                                                            \
    s16x8 a0_ = *(const s16x8*)&AS[P][abase + (2 * (Q)) * 1024 + sl0];         \
    s16x8 a1_ = *(const s16x8*)&AS[P][abase + (2 * (Q)) * 1024 + sl1];         \
    s16x8 a2_ = *(const s16x8*)&AS[P][abase + (2 * (Q) + 1) * 1024 + sl0];     \
    s16x8 a3_ = *(const s16x8*)&AS[P][abase + (2 * (Q) + 1) * 1024 + sl1];     \
    if ((Q) == 0) {                                                            \
      _Pragma("unroll")                                                        \
      for (int nf = 0; nf < 4; ++nf) {                                         \
        bq[nf][0] = *(const s16x8*)&BS[P][bbase + nf * 1024 + sl0];            \
        bq[nf][1] = *(const s16x8*)&BS[P][bbase + nf * 1024 + sl1];            \
      }                                                                        \
    }                                                                          \
    STAGE;                                                                     \
    VM;                                                                        \
    __builtin_amdgcn_s_barrier();                                              \
    asm volatile("s_waitcnt lgkmcnt(0)" ::: "memory");                         \
    __builtin_amdgcn_s_setprio(1);                                             \
    _Pragma("unroll")                                                          \
    for (int nf = 0; nf < 4; ++nf) {                                           \
      acc[2*(Q)][nf]   = __builtin_amdgcn_mfma_f32_16x16x32_bf16(a0_, bq[nf][0], acc[2*(Q)][nf], 0, 0, 0);   \
      acc[2*(Q)+1][nf] = __builtin_amdgcn_mfma_f32_16x16x32_bf16(a2_, bq[nf][0], acc[2*(Q)+1][nf], 0, 0, 0); \
    }                                                                          \
    _Pragma("unroll")                                                          \
    for (int nf = 0; nf < 4; ++nf) {                                           \
      acc[2*(Q)][nf]   = __builtin_amdgcn_mfma_f32_16x16x32_bf16(a1_, bq[nf][1], acc[2*(Q)][nf], 0, 0, 0);   \
      acc[2*(Q)+1][nf] = __builtin_amdgcn_mfma_f32_16x16x32_bf16(a3_, bq[nf][1], acc[2*(Q)+1][nf], 0, 0, 0); \
    }                                                                          \
    __builtin_amdgcn_s_setprio(0);                                             \
    __builtin_amdgcn_s_barrier();                                              \
  }

#define VM6 asm volatile("s_waitcnt vmcnt(6)" ::: "memory")
#define VM0 asm volatile("s_waitcnt vmcnt(0)" ::: "memory")
#define NOP (void)0

  // prologue: tile0 (buf0) full + tile1 (buf1) B0,B1,A0
  STG(&BS[0][0],    Bb, n0,       0);
  STG(&BS[0][8192], Bb, n0 + 128, 0);
  STG(&AS[0][0],    Ab, m0,       0);
  STG(&AS[0][8192], Ab, m0 + 128, 0);
  STG(&BS[1][0],    Bb, n0,       64);
  STG(&BS[1][8192], Bb, n0 + 128, 64);
  STG(&AS[1][0],    Ab, m0,       64);
  VM6;                            // 14 issued, drain to 6 -> tile0 landed
  __builtin_amdgcn_s_barrier();

  for (int j = 0; j < 7; ++j) {
    const int kb = j * 128;
    PHASE(0, 0, NOP, STG(&AS[1][8192], Ab, m0 + 128, kb + 64));
    PHASE(0, 1, NOP, STG(&BS[0][0],    Bb, n0,       kb + 128));
    PHASE(0, 2, NOP, STG(&BS[0][8192], Bb, n0 + 128, kb + 128));
    PHASE(0, 3, VM6, STG(&AS[0][0],    Ab, m0,       kb + 128));
    PHASE(1, 0, NOP, STG(&AS[0][8192], Ab, m0 + 128, kb + 128));
    PHASE(1, 1, NOP, STG(&BS[1][0],    Bb, n0,       kb + 192));
    PHASE(1, 2, NOP, STG(&BS[1][8192], Bb, n0 + 128, kb + 192));
    PHASE(1, 3, VM6, STG(&AS[1][0],    Ab, m0,       kb + 192));
  }
  // final iteration: tiles 14 (buf0), 15 (buf1); only t15.A1 left to stage
  PHASE(0, 0, NOP, STG(&AS[1][8192], Ab, m0 + 128, 960));
  PHASE(0, 1, NOP, NOP);
  PHASE(0, 2, NOP, NOP);
  PHASE(0, 3, VM0, NOP);
  PHASE(1, 0, NOP, NOP);
  PHASE(1, 1, NOP, NOP);
  PHASE(1, 2, NOP, NOP);
  PHASE(1, 3, NOP, NOP);

#undef STG
#undef PHASE
#undef VM6
#undef VM0
#undef NOP

  // epilogue: C/D layout col=lane&15, row=(lane>>4)*4+qq
#pragma unroll
  for (int mf = 0; mf < 8; ++mf)
#pragma unroll
    for (int nf = 0; nf < 4; ++nf) {
      int m = m0 + wr * 128 + mf * 16 + lq * 4;
      int n = n0 + wc * 64 + nf * 16 + lr;
#pragma unroll
      for (int qq = 0; qq < 4; ++qq)
        Cb[(size_t)(m + qq) * D_ + n] = acc[mf][nf][qq];
    }
}

// ---------------------------------------------------------------------------
// bf16 MFMA GEMM (R3 single-buffer 128x128, for G1/G2): C = A @ Bt^T
// ---------------------------------------------------------------------------
template<bool BF32, bool TANH_, bool WT, bool OB16>
__global__ __launch_bounds__(256, 2)
void gemm_bt(const short* __restrict__ Ab, const void* __restrict__ Bv,
             void* __restrict__ Cv, int M, int N, int K,
             long sA, long sB, long sC, int gx, int gy) {
  __shared__ __align__(16) short As[128 * 64];
  __shared__ __align__(16) short Bs[128 * 64];
  unsigned nwg = gridDim.x;
  unsigned L = blockIdx.x;
  unsigned xcd = L & 7u, base = L >> 3;
  unsigned q = nwg >> 3, r = nwg & 7u;
  unsigned id = (xcd < r ? xcd * (q + 1) : r * (q + 1) + (xcd - r) * q) + base;
  const int gxy = gx * gy;
  const int bz = id / gxy;
  const int rem = id - bz * gxy;
  const int by = rem / gx;
  const int bx = rem - by * gx;

  const int tid = threadIdx.x;
  const int w = tid >> 6, lane = tid & 63;
  const int n0 = bx * 128, m0 = by * 128;
  const int wr = w >> 1, wc = w & 1;
  const int lr = lane & 15, lq = lane >> 4;
  const short* A = Ab + (size_t)sA * bz;
  const short* Bb16 = nullptr; const float* Bf32 = nullptr;
  if (BF32) Bf32 = (const float*)Bv + (size_t)sB * bz;
  else      Bb16 = (const short*)Bv + (size_t)sB * bz;

  f32x4 acc[4][4] = {};
  const int r8 = lane >> 3, c8 = lane & 7;

  for (int k0 = 0; k0 < K; k0 += 64) {
    __syncthreads();
#pragma unroll
    for (int i = 0; i < 4; ++i) {
      int chunk = w * 4 + i;
      int row = chunk * 8 + r8;
      gll16(A + (size_t)(m0 + row) * K + k0 + c8 * 8, As + chunk * 512);
    }
    if (!BF32) {
#pragma unroll
      for (int i = 0; i < 4; ++i) {
        int chunk = w * 4 + i;
        int row = chunk * 8 + r8;
        gll16(Bb16 + (size_t)(n0 + row) * K + k0 + c8 * 8, Bs + chunk * 512);
      }
    } else {
#pragma unroll
      for (int u = 0; u < 4; ++u) {
        int c = tid * 4 + u;
        int row = c >> 3, k8 = c & 7;
        const float* gp = Bf32 + (size_t)(n0 + row) * K + k0 + k8 * 8;
        float4 f0 = *(const float4*)gp;
        float4 f1 = *(const float4*)(gp + 4);
        s16x8 p;
        p[0] = f2b(f0.x); p[1] = f2b(f0.y); p[2] = f2b(f0.z); p[3] = f2b(f0.w);
        p[4] = f2b(f1.x); p[5] = f2b(f1.y); p[6] = f2b(f1.z); p[7] = f2b(f1.w);
        *(s16x8*)&Bs[row * 64 + k8 * 8] = p;
      }
    }
    __syncthreads();
#pragma unroll
    for (int kk = 0; kk < 2; ++kk) {
      s16x8 a[4], b[4];
#pragma unroll
      for (int mf = 0; mf < 4; ++mf)
        a[mf] = *(const s16x8*)&As[(wr * 64 + mf * 16 + lr) * 64 + kk * 32 + lq * 8];
#pragma unroll
      for (int nf = 0; nf < 4; ++nf)
        b[nf] = *(const s16x8*)&Bs[(wc * 64 + nf * 16 + lr) * 64 + kk * 32 + lq * 8];
#pragma unroll
      for (int mf = 0; mf < 4; ++mf)
#pragma unroll
        for (int nf = 0; nf < 4; ++nf)
          acc[mf][nf] = __builtin_amdgcn_mfma_f32_16x16x32_bf16(
              a[mf], b[nf], acc[mf][nf], 0, 0, 0);
    }
  }

  if (WT) {
    if (OB16) {
      short* C = (short*)Cv + (size_t)sC * bz;
#pragma unroll
      for (int mf = 0; mf < 4; ++mf)
#pragma unroll
        for (int nf = 0; nf < 4; ++nf) {
          int mbase = m0 + wr * 64 + mf * 16 + lq * 4;
          int n = n0 + wc * 64 + nf * 16 + lr;
          s16x4 pk;
#pragma unroll
          for (int qq = 0; qq < 4; ++qq) {
            float v = acc[mf][nf][qq];
            if (TANH_) v = tanhf(v);
            pk[qq] = f2b(v);
          }
          *(s16x4*)(C + (size_t)n * M + mbase) = pk;
        }
    } else {
      float* C = (float*)Cv + (size_t)sC * bz;
#pragma unroll
      for (int mf = 0; mf < 4; ++mf)
#pragma unroll
        for (int nf = 0; nf < 4; ++nf) {
          int mbase = m0 + wr * 64 + mf * 16 + lq * 4;
          int n = n0 + wc * 64 + nf * 16 + lr;
#pragma unroll
          for (int qq = 0; qq < 4; ++qq) {
            float v = acc[mf][nf][qq];
            if (TANH_) v = tanhf(v);
            C[(size_t)n * M + mbase + qq] = v;
          }
        }
    }
  } else {
    float* C = (float*)Cv + (size_t)sC * bz;
#pragma unroll
    for (int mf = 0; mf < 4; ++mf)
#pragma unroll
      for (int nf = 0; nf < 4; ++nf) {
        int m = m0 + wr * 64 + mf * 16 + lq * 4;
        int n = n0 + wc * 64 + nf * 16 + lr;
#pragma unroll
        for (int qq = 0; qq < 4; ++qq) {
          float v = acc[mf][nf][qq];
          if (TANH_) v = tanhf(v);
          C[(size_t)(m + qq) * N + n] = v;
        }
      }
  }
}

// ---------------------------------------------------------------------------
// transpose + fp32->bf16: src [z][R][C] fp32 -> dst [z][C][R] bf16. 64x64 tiles.
// ---------------------------------------------------------------------------
__global__ __launch_bounds__(256)
void transpose_cvt(const float* __restrict__ src, short* __restrict__ dst,
                   int R, int C) {
  __shared__ float sh[64][68];
  const int tid = threadIdx.x;
  const float* s = src + (size_t)blockIdx.z * R * C;
  short* d = dst + (size_t)blockIdx.z * R * C;
  const int r0 = blockIdx.y * 64, c0 = blockIdx.x * 64;
#pragma unroll
  for (int u = 0; u < 4; ++u) {
    int e = tid + u * 256;
    int rr = e >> 4, cc4 = (e & 15) * 4;
    *(float4*)&sh[rr][cc4] = *(const float4*)&s[(size_t)(r0 + rr) * C + c0 + cc4];
  }
  __syncthreads();
#pragma unroll
  for (int u = 0; u < 4; ++u) {
    int e = tid + u * 256;
    int dr = e >> 4, tc4 = (e & 15) * 4;
    s16x4 pk;
#pragma unroll
    for (int j = 0; j < 4; ++j) pk[j] = f2b(sh[tc4 + j][dr]);
    *(s16x4*)&d[(size_t)(c0 + dr) * R + r0 + tc4] = pk;
  }
}

// ---------------------------------------------------------------------------
// in-place row softmax on bf16 [nb][T][T]; one wave per row, 16 elems/lane
// ---------------------------------------------------------------------------
__global__ __launch_bounds__(256)
void softmax_rows(short* __restrict__ St) {
  const int w = threadIdx.x >> 6, lane = threadIdx.x & 63;
  short* rp = St + ((size_t)blockIdx.y * T_ + blockIdx.x * 4 + w) * T_;
  s16x8 v0 = *(const s16x8*)&rp[lane * 16];
  s16x8 v1 = *(const s16x8*)&rp[lane * 16 + 8];
  float f[16];
#pragma unroll
  for (int j = 0; j < 8; ++j) { f[j] = b2f(v0[j]); f[j + 8] = b2f(v1[j]); }
  float m = f[0];
#pragma unroll
  for (int j = 1; j < 16; ++j) m = fmaxf(m, f[j]);
#pragma unroll
  for (int o = 32; o; o >>= 1) m = fmaxf(m, __shfl_xor(m, o));
  float ssum = 0.f;
#pragma unroll
  for (int j = 0; j < 16; ++j) { f[j] = __expf(f[j] - m); ssum += f[j]; }
#pragma unroll
  for (int o = 32; o; o >>= 1) ssum += __shfl_xor(ssum, o);
  float inv = 1.0f / ssum;
#pragma unroll
  for (int j = 0; j < 8; ++j) { v0[j] = f2b(f[j] * inv); v1[j] = f2b(f[j + 8] * inv); }
  *(s16x8*)&rp[lane * 16] = v0;
  *(s16x8*)&rp[lane * 16 + 8] = v1;
}

extern "C" void kernel_launch(void* const* d_in, const int* in_sizes, int n_in,
                              void* d_out, int out_size, void* d_ws, size_t ws_size,
                              hipStream_t stream) {
  const float* x  = (const float*)d_in[0];   // [B,T,D]
  const float* W1 = (const float*)d_in[1];   // [D,A]
  const float* W2 = (const float*)d_in[2];   // [A,T]
  float* out = (float*)d_out;                // [B,T,D] fp32

  // ws layout (bf16/shorts): xt[B,D,T] | W1t[A,D] | W2t[T,A] | H[B,T,A] | St[nb,T,T]
  short* xt  = (short*)d_ws;
  short* W1t = xt + (size_t)B_ * D_ * T_;
  short* W2t = W1t + (size_t)A_ * D_;
  short* H   = W2t + (size_t)T_ * A_;
  short* St  = H + (size_t)B_ * T_ * A_;
  size_t fixed_bytes = (size_t)(St - xt) * sizeof(short);
  long avail = (long)ws_size - (long)fixed_bytes;
  long per_b = (long)T_ * T_ * sizeof(short);
  int chunk = (int)(avail > 0 ? avail / per_b : 0);
  if (chunk > B_) chunk = B_;
  if (chunk < 1) chunk = 1;

  // prep: transposed bf16 copies
  transpose_cvt<<<dim3(D_ / 64, T_ / 64, B_), 256, 0, stream>>>(x, xt, T_, D_);
  transpose_cvt<<<dim3(A_ / 64, D_ / 64, 1), 256, 0, stream>>>(W1, W1t, D_, A_);
  transpose_cvt<<<dim3(T_ / 64, A_ / 64, 1), 256, 0, stream>>>(W2, W2t, A_, T_);

  // G1: H^T = W1t @ x^T (M=A,N=T,K=D), transposed write -> H[t][a] bf16, tanh
  gemm_bt<true, true, true, true><<<(T_ / 128) * (A_ / 128) * B_, 256, 0, stream>>>(
      W1t, x, H, A_, T_, D_, 0, (long)T_ * D_, (long)T_ * A_,
      T_ / 128, A_ / 128);

  for (int b0 = 0; b0 < B_; b0 += chunk) {
    int nb = B_ - b0; if (nb > chunk) nb = chunk;
    // G2: S[t,s] = H @ W2t^T (M=T,N=T,K=A), transposed write -> St[s][t] bf16
    gemm_bt<false, false, true, true><<<(T_ / 128) * (T_ / 128) * nb, 256, 0, stream>>>(
        H + (size_t)b0 * T_ * A_, W2t, St, T_, T_, A_,
        (long)T_ * A_, 0, (long)T_ * T_,
        T_ / 128, T_ / 128);
    // softmax over t = rows of St, in place, bf16 out
    softmax_rows<<<dim3(T_ / 4, nb), 256, 0, stream>>>(St);
    // G4 (8-phase 256^2): out[s,d] = Pt @ xt^T, fp32 write
    gemm4_8ph<<<12 * nb, 512, 0, stream>>>(
        St, xt + (size_t)b0 * (size_t)D_ * T_, out + (size_t)b0 * (size_t)T_ * D_);
  }
}